// Round 9
// baseline (507.002 us; speedup 1.0000x reference)
//
#include <hip/hip_runtime.h>
#include <math.h>

#define B_ 32
#define L_ 2049
#define E_ 1024
#define H_ 16
#define NT_ 8
#define STILE 256

// workspace layout (float offsets) — identical footprint to round 1 (known-safe)
#define OFF_Q     0
#define OFF_T     (OFF_Q + B_*E_)
#define OFF_QBK   (OFF_T + B_*H_*E_)
#define OFF_M     (OFF_QBK + B_*H_)
#define OFF_L     (OFF_M + B_*NT_*H_)
#define OFF_U     (OFF_L + B_*NT_*H_)
#define OFF_ATTN  (OFF_U + B_*H_*E_)
#define OFF_Y     (OFF_ATTN + B_*E_)
#define OFF_UP    (OFF_Y + B_*E_)

// ---------------------------------------------------------------- generic 32xE GEMM:
// C[b][j] = sum_k A[b*As + kbase + k] * W[j][k] + bias[j] (+ resid[b*Rs + j])
// mode 1 (vproj): kbase = (j>>6)*1024 (per-head slice of u). Grid: 512 blocks, j-tile=2.
__global__ __launch_bounds__(256) void k_gemm32(const float* __restrict__ A, long long As, int mode,
                                                const float* __restrict__ W,
                                                const float* __restrict__ bias,
                                                const float* __restrict__ resid, long long Rs,
                                                float* __restrict__ C) {
    __shared__ float wls[2 * 1056];  // 2 swizzled W rows
    const int j0 = blockIdx.x * 2, tid = threadIdx.x;
    #pragma unroll
    for (int k = 0; k < 2; ++k) {
        int idx4 = k * 256 + tid;
        int row = idx4 >> 8, c4 = idx4 & 255;
        float4 v = *(const float4*)(W + (size_t)(j0 + row) * E_ + 4 * c4);
        *(float4*)&wls[row * 1056 + 4 * c4 + ((c4 >> 5) << 2)] = v;  // swizzle: k + (k>>7)*4
    }
    __syncthreads();
    const int bb = tid >> 3, kseg = tid & 7;
    const long long kbase = (mode == 1) ? (long long)(j0 >> 6) * E_ : 0;
    const float* arow = A + (size_t)bb * As + kbase + kseg * 128;
    float a0 = 0.f, a1 = 0.f;
    #pragma unroll 4
    for (int i = 0; i < 32; ++i) {
        float4 av = *(const float4*)(arow + 4 * i);
        const float* wb = &wls[kseg * 132 + 4 * i];
        float4 w0 = *(const float4*)(wb);
        float4 w1 = *(const float4*)(wb + 1056);
        a0 += av.x * w0.x + av.y * w0.y + av.z * w0.z + av.w * w0.w;
        a1 += av.x * w1.x + av.y * w1.y + av.z * w1.z + av.w * w1.w;
    }
    #pragma unroll
    for (int off = 4; off; off >>= 1) {
        a0 += __shfl_down(a0, off, 8);
        a1 += __shfl_down(a1, off, 8);
    }
    if (kseg == 0) {
        float r0 = a0 + bias[j0], r1 = a1 + bias[j0 + 1];
        if (resid) {
            r0 += resid[(size_t)bb * Rs + j0];
            r1 += resid[(size_t)bb * Rs + j0 + 1];
        }
        C[(size_t)bb * E_ + j0] = r0;
        C[(size_t)bb * E_ + j0 + 1] = r1;
    }
}

// ---------------------------------------------------------------- t = 0.125*q_h@Wk_h ; qbk
// grid (16 h, 16 e-tiles of 64), 256 thr
__global__ __launch_bounds__(256) void k_tproj(const float* __restrict__ Wk,
                                               const float* __restrict__ bk,
                                               float* __restrict__ ws) {
    __shared__ float qs[64 * 33];   // [d][b]
    __shared__ float wls[64 * 68];  // [d][e] padded/aligned
    const int h = blockIdx.x, e0 = blockIdx.y * 64, tid = threadIdx.x;
    const float* q = ws + OFF_Q;
    #pragma unroll
    for (int k = 0; k < 8; ++k) {
        int idx = k * 256 + tid;
        int b = idx >> 6, d = idx & 63;
        qs[d * 33 + b] = q[(size_t)b * E_ + 64 * h + d];
    }
    #pragma unroll
    for (int k = 0; k < 4; ++k) {
        int idx4 = k * 256 + tid;
        int d = idx4 >> 4, c4 = idx4 & 15;
        float4 v = *(const float4*)(Wk + (size_t)(64 * h + d) * E_ + e0 + 4 * c4);
        *(float4*)&wls[d * 68 + 4 * c4] = v;
    }
    __syncthreads();
    const int el = tid & 63, bq8 = tid >> 6;
    float acc[8];
    #pragma unroll
    for (int i = 0; i < 8; ++i) acc[i] = 0.f;
    for (int d = 0; d < 64; ++d) {
        float wv = wls[d * 68 + el];
        #pragma unroll
        for (int i = 0; i < 8; ++i) acc[i] += qs[d * 33 + (bq8 * 8 + i)] * wv;
    }
    float* t = ws + OFF_T;
    #pragma unroll
    for (int i = 0; i < 8; ++i)
        t[((size_t)(bq8 * 8 + i) * H_ + h) * E_ + e0 + el] = acc[i] * 0.125f;
    if (e0 == 0 && tid < 32) {
        float s = 0.f;
        for (int d = 0; d < 64; ++d) s += qs[d * 33 + tid] * bk[64 * h + d];
        ws[OFF_QBK + tid * H_ + h] = s * 0.125f;
    }
}

// ---------------------------------------------------------------- fused scores/softmax/u_part
// Round-9: 512 threads + __launch_bounds__(512, 2). VGPR history (124 @512thr, 64 @1024thr)
// matches a backend default of 2 blocks/CU; this kernel is pinned to 1 block/CU by grid
// (256 blocks) and LDS (81 KB), so half the RF was unused. (512,2) raises the cap to 256
// VGPR at zero occupancy cost; the headroom funds explicit PREFETCH (the 165-175 us
// plateau across r4-r8 is latency exposure, not pipe saturation):
//   Phase 1: round-8 partition (e-half x s-quarter, acc[16][4]); next-chunk x (4xfloat4)
//     issued before the 256-FMA compute (~1000 cyc cover for ~900 cyc HBM latency).
//   Phase 2: barrier-free round-8 partition (4 heads x 8 cols/lane); rows in groups of
//     4 with next-group x+w prefetch (~500 cyc cover for L2/L3 latency).
__global__ __launch_bounds__(512, 2) void k_attn_core(const float* __restrict__ x,
                                                      float* __restrict__ ws) {
    const int tile = blockIdx.x, b = blockIdx.y, tid = threadIdx.x;
    const int s0t = tile * STILE;
    const float* tmat = ws + OFF_T + (size_t)b * H_ * E_;
    const float* xb = x + (size_t)(b * L_ + 1 + s0t) * E_;

    __shared__ float smem[16384];   // t[16][1024]
    __shared__ float wl[256 * 16];  // hi-half partial scores, then softmax weights [s][h]
    __shared__ float pmax[64], psum[64], msh[16];

    const int lane = tid & 63, w = tid >> 6;
    const int g = lane & 3, ssub = lane >> 2;

    // ---- stage full t (16x1024 = 64 KB), straight copy ----
    #pragma unroll
    for (int k = 0; k < 8; ++k) {
        int idx4 = k * 512 + tid;
        *(float4*)&smem[4 * idx4] = *(const float4*)(tmat + 4 * idx4);
    }
    __syncthreads();

    // ================= phase 1: partial scores (no barriers inside) =================
    // wave = (eh1 e-half, sq1 s-quarter); lane row k: sq1*64 + ssub + 16k
    const int eh1 = w >> 2, sq1 = w & 3;
    const int ehalf = eh1 * 512;
    const int rbase1 = sq1 * 64 + ssub;

    float acc[16][4];
    #pragma unroll
    for (int h = 0; h < 16; ++h) {
        acc[h][0] = 0.f; acc[h][1] = 0.f; acc[h][2] = 0.f; acc[h][3] = 0.f;
    }
    {
        const float* xq = xb + (size_t)rbase1 * E_ + ehalf + 4 * g;
        const float* tb = &smem[ehalf + 4 * g];
        float4 x0 = *(const float4*)(xq);
        float4 x1 = *(const float4*)(xq + 16 * E_);
        float4 x2 = *(const float4*)(xq + 32 * E_);
        float4 x3 = *(const float4*)(xq + 48 * E_);
        #pragma unroll 1
        for (int c = 0; c < 32; ++c) {
            const int e0 = 16 * c;
            float4 n0, n1, n2, n3;
            if (c + 1 < 32) {                       // prefetch next chunk's x
                n0 = *(const float4*)(xq + e0 + 16);
                n1 = *(const float4*)(xq + 16 * E_ + e0 + 16);
                n2 = *(const float4*)(xq + 32 * E_ + e0 + 16);
                n3 = *(const float4*)(xq + 48 * E_ + e0 + 16);
            }
            #pragma unroll
            for (int h = 0; h < 16; ++h) {
                float4 t0 = *(const float4*)(tb + h * E_ + e0);
                acc[h][0] += t0.x * x0.x + t0.y * x0.y + t0.z * x0.z + t0.w * x0.w;
                acc[h][1] += t0.x * x1.x + t0.y * x1.y + t0.z * x1.z + t0.w * x1.w;
                acc[h][2] += t0.x * x2.x + t0.y * x2.y + t0.z * x2.z + t0.w * x2.w;
                acc[h][3] += t0.x * x3.x + t0.y * x3.y + t0.z * x3.z + t0.w * x3.w;
            }
            if (c + 1 < 32) { x0 = n0; x1 = n1; x2 = n2; x3 = n3; }
        }
    }
    // reduce over the 4 e-granule lanes (g); all g-lanes end with the full sums
    #pragma unroll
    for (int h = 0; h < 16; ++h) {
        #pragma unroll
        for (int k = 0; k < 4; ++k) {
            float v = acc[h][k];
            v += __shfl_xor(v, 1, 64);
            v += __shfl_xor(v, 2, 64);
            acc[h][k] = v;
        }
    }
    // hi e-half waves deposit partials into wl (g picks the h-quad; static reg idx)
    if (eh1 == 1) {
        #pragma unroll
        for (int k = 0; k < 4; ++k) {
            const int row = rbase1 + 16 * k;
            if (g == 0)      *(float4*)&wl[row * 16 + 0]  = make_float4(acc[0][k],  acc[1][k],  acc[2][k],  acc[3][k]);
            else if (g == 1) *(float4*)&wl[row * 16 + 4]  = make_float4(acc[4][k],  acc[5][k],  acc[6][k],  acc[7][k]);
            else if (g == 2) *(float4*)&wl[row * 16 + 8]  = make_float4(acc[8][k],  acc[9][k],  acc[10][k], acc[11][k]);
            else             *(float4*)&wl[row * 16 + 12] = make_float4(acc[12][k], acc[13][k], acc[14][k], acc[15][k]);
        }
    }
    __syncthreads();  // E1: hi partials visible

    // ================= softmax partials (lo e-half waves hold full scores) ==========
    if (eh1 == 0) {
        const float* qbkp = ws + OFF_QBK + b * H_;
        #pragma unroll
        for (int h = 0; h < 16; ++h) {
            float qb = qbkp[h];
            #pragma unroll
            for (int k = 0; k < 4; ++k)
                acc[h][k] += wl[(rbase1 + 16 * k) * 16 + h] + qb;
        }
        #pragma unroll
        for (int h = 0; h < 16; ++h) {
            float v = fmaxf(fmaxf(acc[h][0], acc[h][1]), fmaxf(acc[h][2], acc[h][3]));
            v = fmaxf(v, __shfl_xor(v, 4, 64));
            v = fmaxf(v, __shfl_xor(v, 8, 64));
            v = fmaxf(v, __shfl_xor(v, 16, 64));
            v = fmaxf(v, __shfl_xor(v, 32, 64));
            if (lane == 0) pmax[sq1 * 16 + h] = v;
        }
    }
    __syncthreads();  // B1
    if (tid < 16) {
        float M = pmax[tid];
        M = fmaxf(M, pmax[16 + tid]);
        M = fmaxf(M, pmax[32 + tid]);
        M = fmaxf(M, pmax[48 + tid]);
        msh[tid] = M;
        ws[OFF_M + (size_t)(b * NT_ + tile) * H_ + tid] = M;
    }
    __syncthreads();  // B2
    if (eh1 == 0) {
        #pragma unroll
        for (int h = 0; h < 16; ++h) {
            float M = msh[h];
            acc[h][0] = __expf(acc[h][0] - M);
            acc[h][1] = __expf(acc[h][1] - M);
            acc[h][2] = __expf(acc[h][2] - M);
            acc[h][3] = __expf(acc[h][3] - M);
        }
        #pragma unroll
        for (int k = 0; k < 4; ++k) {
            const int row = rbase1 + 16 * k;
            if (g == 0)      *(float4*)&wl[row * 16 + 0]  = make_float4(acc[0][k],  acc[1][k],  acc[2][k],  acc[3][k]);
            else if (g == 1) *(float4*)&wl[row * 16 + 4]  = make_float4(acc[4][k],  acc[5][k],  acc[6][k],  acc[7][k]);
            else if (g == 2) *(float4*)&wl[row * 16 + 8]  = make_float4(acc[8][k],  acc[9][k],  acc[10][k], acc[11][k]);
            else             *(float4*)&wl[row * 16 + 12] = make_float4(acc[12][k], acc[13][k], acc[14][k], acc[15][k]);
        }
        #pragma unroll
        for (int h = 0; h < 16; ++h) {
            float v = acc[h][0] + acc[h][1] + acc[h][2] + acc[h][3];
            v += __shfl_xor(v, 4, 64);
            v += __shfl_xor(v, 8, 64);
            v += __shfl_xor(v, 16, 64);
            v += __shfl_xor(v, 32, 64);
            if (lane == 0) psum[sq1 * 16 + h] = v;
        }
    }
    __syncthreads();  // B3: weights complete in wl
    if (tid < 16) {
        float Ls = psum[tid] + psum[16 + tid] + psum[32 + tid] + psum[48 + tid];
        ws[OFF_L + (size_t)(b * NT_ + tile) * H_ + tid] = Ls;
    }

    // ================= phase 2 (barrier-free): u[h][e] = sum_s w[s][h]*x[s][e] ======
    // wave w owns cols [128w,128w+128); lane = (hg head-quad, cl col-octet).
    // Rows in groups of 4 with next-group x+w prefetch (statically indexed arrays).
    const int hg = lane >> 4, cl = lane & 15;
    float4 ua[4][2];
    #pragma unroll
    for (int j = 0; j < 4; ++j) {
        ua[j][0] = make_float4(0.f, 0.f, 0.f, 0.f);
        ua[j][1] = make_float4(0.f, 0.f, 0.f, 0.f);
    }
    const float* xq2 = xb + 128 * w + 8 * cl;
    const float* wq2 = &wl[4 * hg];
    float4 px[4][2], pw[4];
    #pragma unroll
    for (int j = 0; j < 4; ++j) {
        px[j][0] = *(const float4*)(xq2 + (size_t)j * E_);
        px[j][1] = *(const float4*)(xq2 + (size_t)j * E_ + 4);
        pw[j]    = *(const float4*)(wq2 + j * 16);
    }
    #pragma unroll 1
    for (int rg = 0; rg < 64; ++rg) {
        float4 nx[4][2], nw[4];
        if (rg + 1 < 64) {                          // prefetch next 4-row group
            const int rb2 = (rg + 1) * 4;
            #pragma unroll
            for (int j = 0; j < 4; ++j) {
                nx[j][0] = *(const float4*)(xq2 + (size_t)(rb2 + j) * E_);
                nx[j][1] = *(const float4*)(xq2 + (size_t)(rb2 + j) * E_ + 4);
                nw[j]    = *(const float4*)(wq2 + (rb2 + j) * 16);
            }
        }
        #pragma unroll
        for (int j = 0; j < 4; ++j) {
            const float4 wv = pw[j];
            const float4 xv0 = px[j][0], xv1 = px[j][1];
            ua[0][0].x += wv.x * xv0.x; ua[0][0].y += wv.x * xv0.y; ua[0][0].z += wv.x * xv0.z; ua[0][0].w += wv.x * xv0.w;
            ua[0][1].x += wv.x * xv1.x; ua[0][1].y += wv.x * xv1.y; ua[0][1].z += wv.x * xv1.z; ua[0][1].w += wv.x * xv1.w;
            ua[1][0].x += wv.y * xv0.x; ua[1][0].y += wv.y * xv0.y; ua[1][0].z += wv.y * xv0.z; ua[1][0].w += wv.y * xv0.w;
            ua[1][1].x += wv.y * xv1.x; ua[1][1].y += wv.y * xv1.y; ua[1][1].z += wv.y * xv1.z; ua[1][1].w += wv.y * xv1.w;
            ua[2][0].x += wv.z * xv0.x; ua[2][0].y += wv.z * xv0.y; ua[2][0].z += wv.z * xv0.z; ua[2][0].w += wv.z * xv0.w;
            ua[2][1].x += wv.z * xv1.x; ua[2][1].y += wv.z * xv1.y; ua[2][1].z += wv.z * xv1.z; ua[2][1].w += wv.z * xv1.w;
            ua[3][0].x += wv.w * xv0.x; ua[3][0].y += wv.w * xv0.y; ua[3][0].z += wv.w * xv0.z; ua[3][0].w += wv.w * xv0.w;
            ua[3][1].x += wv.w * xv1.x; ua[3][1].y += wv.w * xv1.y; ua[3][1].z += wv.w * xv1.z; ua[3][1].w += wv.w * xv1.w;
        }
        if (rg + 1 < 64) {
            #pragma unroll
            for (int j = 0; j < 4; ++j) { px[j][0] = nx[j][0]; px[j][1] = nx[j][1]; pw[j] = nw[j]; }
        }
    }
    float* up = ws + OFF_UP + ((size_t)((b * NT_ + tile) * H_ + 4 * hg)) * E_ + 128 * w + 8 * cl;
    #pragma unroll
    for (int j = 0; j < 4; ++j) {
        *(float4*)(up + (size_t)j * E_)     = ua[j][0];
        *(float4*)(up + (size_t)j * E_ + 4) = ua[j][1];
    }
}

// ---------------------------------------------------------------- combine partial tiles
__global__ __launch_bounds__(256) void k_combine(float* __restrict__ ws) {
    const int b = blockIdx.x, h = blockIdx.y, tid = threadIdx.x;
    float m[NT_], l[NT_], f[NT_];
    float M = -1e30f;
    #pragma unroll
    for (int tg = 0; tg < NT_; ++tg) {
        m[tg] = ws[OFF_M + (b * NT_ + tg) * H_ + h];
        l[tg] = ws[OFF_L + (b * NT_ + tg) * H_ + h];
        M = fmaxf(M, m[tg]);
    }
    float Ls = 0.f;
    #pragma unroll
    for (int tg = 0; tg < NT_; ++tg) {
        f[tg] = __expf(m[tg] - M);
        Ls += f[tg] * l[tg];
    }
    const float inv = 1.f / Ls;
    float4 a = make_float4(0.f, 0.f, 0.f, 0.f);
    #pragma unroll
    for (int tg = 0; tg < NT_; ++tg) {
        float4 v = *(const float4*)(ws + OFF_UP + (size_t)((b * NT_ + tg) * H_ + h) * E_ + 4 * tid);
        a.x += f[tg] * v.x; a.y += f[tg] * v.y; a.z += f[tg] * v.z; a.w += f[tg] * v.w;
    }
    a.x *= inv; a.y *= inv; a.z *= inv; a.w *= inv;
    *(float4*)(ws + OFF_U + (size_t)(b * H_ + h) * E_ + 4 * tid) = a;
}

// ---------------------------------------------------------------- LayerNorm -> out
__global__ __launch_bounds__(256) void k_ln(const float* __restrict__ ws,
                                            const float* __restrict__ g,
                                            const float* __restrict__ be,
                                            float* __restrict__ out) {
    const int b = blockIdx.x, tid = threadIdx.x;
    const float* y = ws + OFF_Y + (size_t)b * E_;
    float4 v = *(const float4*)(y + 4 * tid);
    float s = v.x + v.y + v.z + v.w;
    float s2 = v.x * v.x + v.y * v.y + v.z * v.z + v.w * v.w;
    for (int o = 32; o; o >>= 1) {
        s += __shfl_down(s, o, 64);
        s2 += __shfl_down(s2, o, 64);
    }
    __shared__ float rs[4], rs2[4];
    int ww = tid >> 6;
    if ((tid & 63) == 0) { rs[ww] = s; rs2[ww] = s2; }
    __syncthreads();
    float S = rs[0] + rs[1] + rs[2] + rs[3];
    float S2 = rs2[0] + rs2[1] + rs2[2] + rs2[3];
    float mean = S * (1.f / 1024.f);
    float var = S2 * (1.f / 1024.f) - mean * mean;
    float r = rsqrtf(var + 1e-5f);
    float4 gv = *(const float4*)(g + 4 * tid);
    float4 bb2 = *(const float4*)(be + 4 * tid);
    float4 o;
    o.x = (v.x - mean) * r * gv.x + bb2.x;
    o.y = (v.y - mean) * r * gv.y + bb2.y;
    o.z = (v.z - mean) * r * gv.z + bb2.z;
    o.w = (v.w - mean) * r * gv.w + bb2.w;
    *(float4*)(out + (size_t)b * E_ + 4 * tid) = o;
}

extern "C" void kernel_launch(void* const* d_in, const int* in_sizes, int n_in,
                              void* d_out, int out_size, void* d_ws, size_t ws_size,
                              hipStream_t stream) {
    const float* x  = (const float*)d_in[0];
    const float* Wq = (const float*)d_in[1];
    const float* bq = (const float*)d_in[2];
    const float* Wk = (const float*)d_in[3];
    const float* bk = (const float*)d_in[4];
    const float* Wv = (const float*)d_in[5];
    const float* bv = (const float*)d_in[6];
    const float* Wo = (const float*)d_in[7];
    const float* bo = (const float*)d_in[8];
    const float* g  = (const float*)d_in[9];
    const float* be = (const float*)d_in[10];
    float* ws = (float*)d_ws;
    float* out = (float*)d_out;

    // q = cls @ Wq^T + bq
    k_gemm32<<<512, 256, 0, stream>>>(x, (long long)L_ * E_, 0, Wq, bq, nullptr, 0, ws + OFF_Q);
    // t = 0.125 * q_h @ Wk_h ; qbk
    k_tproj<<<dim3(16, 16), 256, 0, stream>>>(Wk, bk, ws);
    // fused attention core (512 threads, 8 waves, 256-VGPR budget, prefetched)
    k_attn_core<<<dim3(NT_, B_), 512, 0, stream>>>(x, ws);
    // combine softmax tiles
    k_combine<<<dim3(B_, H_), 256, 0, stream>>>(ws);
    // attn = Wv_h @ u_h + bv   (per-head K slice of u)
    k_gemm32<<<512, 256, 0, stream>>>(ws + OFF_U, (long long)H_ * E_, 1, Wv, bv, nullptr, 0, ws + OFF_ATTN);
    // y = attn @ Wo^T + bo + cls
    k_gemm32<<<512, 256, 0, stream>>>(ws + OFF_ATTN, (long long)E_, 0, Wo, bo, x, (long long)L_ * E_, ws + OFF_Y);
    // LayerNorm
    k_ln<<<B_, 256, 0, stream>>>(ws, g, be, out);
}

// Round 10
// 495.465 us; speedup vs baseline: 1.0233x; 1.0233x over previous
//
#include <hip/hip_runtime.h>
#include <math.h>

#define B_ 32
#define L_ 2049
#define E_ 1024
#define H_ 16
#define NT_ 8
#define STILE 256

// workspace layout (float offsets) — identical footprint to round 1 (known-safe)
#define OFF_Q     0
#define OFF_T     (OFF_Q + B_*E_)
#define OFF_QBK   (OFF_T + B_*H_*E_)
#define OFF_M     (OFF_QBK + B_*H_)
#define OFF_L     (OFF_M + B_*NT_*H_)
#define OFF_U     (OFF_L + B_*NT_*H_)
#define OFF_ATTN  (OFF_U + B_*H_*E_)
#define OFF_Y     (OFF_ATTN + B_*E_)
#define OFF_UP    (OFF_Y + B_*E_)

// ---------------------------------------------------------------- generic 32xE GEMM:
// C[b][j] = sum_k A[b*As + k] * W[j][k] + bias[j] (+ resid[b*Rs + j])
__global__ __launch_bounds__(256) void k_gemm32(const float* __restrict__ A, long long As, int mode,
                                                const float* __restrict__ W,
                                                const float* __restrict__ bias,
                                                const float* __restrict__ resid, long long Rs,
                                                float* __restrict__ C) {
    __shared__ float wls[2 * 1056];  // 2 swizzled W rows
    const int j0 = blockIdx.x * 2, tid = threadIdx.x;
    #pragma unroll
    for (int k = 0; k < 2; ++k) {
        int idx4 = k * 256 + tid;
        int row = idx4 >> 8, c4 = idx4 & 255;
        float4 v = *(const float4*)(W + (size_t)(j0 + row) * E_ + 4 * c4);
        *(float4*)&wls[row * 1056 + 4 * c4 + ((c4 >> 5) << 2)] = v;  // swizzle: k + (k>>7)*4
    }
    __syncthreads();
    const int bb = tid >> 3, kseg = tid & 7;
    const long long kbase = (mode == 1) ? (long long)(j0 >> 6) * E_ : 0;
    const float* arow = A + (size_t)bb * As + kbase + kseg * 128;
    float a0 = 0.f, a1 = 0.f;
    #pragma unroll 4
    for (int i = 0; i < 32; ++i) {
        float4 av = *(const float4*)(arow + 4 * i);
        const float* wb = &wls[kseg * 132 + 4 * i];
        float4 w0 = *(const float4*)(wb);
        float4 w1 = *(const float4*)(wb + 1056);
        a0 += av.x * w0.x + av.y * w0.y + av.z * w0.z + av.w * w0.w;
        a1 += av.x * w1.x + av.y * w1.y + av.z * w1.z + av.w * w1.w;
    }
    #pragma unroll
    for (int off = 4; off; off >>= 1) {
        a0 += __shfl_down(a0, off, 8);
        a1 += __shfl_down(a1, off, 8);
    }
    if (kseg == 0) {
        float r0 = a0 + bias[j0], r1 = a1 + bias[j0 + 1];
        if (resid) {
            r0 += resid[(size_t)bb * Rs + j0];
            r1 += resid[(size_t)bb * Rs + j0 + 1];
        }
        C[(size_t)bb * E_ + j0] = r0;
        C[(size_t)bb * E_ + j0 + 1] = r1;
    }
}

// ---------------------------------------------------------------- t = 0.125*q_h@Wk_h ; qbk
// grid (16 h, 16 e-tiles of 64), 256 thr
__global__ __launch_bounds__(256) void k_tproj(const float* __restrict__ Wk,
                                               const float* __restrict__ bk,
                                               float* __restrict__ ws) {
    __shared__ float qs[64 * 33];   // [d][b]
    __shared__ float wls[64 * 68];  // [d][e] padded/aligned
    const int h = blockIdx.x, e0 = blockIdx.y * 64, tid = threadIdx.x;
    const float* q = ws + OFF_Q;
    #pragma unroll
    for (int k = 0; k < 8; ++k) {
        int idx = k * 256 + tid;
        int b = idx >> 6, d = idx & 63;
        qs[d * 33 + b] = q[(size_t)b * E_ + 64 * h + d];
    }
    #pragma unroll
    for (int k = 0; k < 4; ++k) {
        int idx4 = k * 256 + tid;
        int d = idx4 >> 4, c4 = idx4 & 15;
        float4 v = *(const float4*)(Wk + (size_t)(64 * h + d) * E_ + e0 + 4 * c4);
        *(float4*)&wls[d * 68 + 4 * c4] = v;
    }
    __syncthreads();
    const int el = tid & 63, bq8 = tid >> 6;
    float acc[8];
    #pragma unroll
    for (int i = 0; i < 8; ++i) acc[i] = 0.f;
    for (int d = 0; d < 64; ++d) {
        float wv = wls[d * 68 + el];
        #pragma unroll
        for (int i = 0; i < 8; ++i) acc[i] += qs[d * 33 + (bq8 * 8 + i)] * wv;
    }
    float* t = ws + OFF_T;
    #pragma unroll
    for (int i = 0; i < 8; ++i)
        t[((size_t)(bq8 * 8 + i) * H_ + h) * E_ + e0 + el] = acc[i] * 0.125f;
    if (e0 == 0 && tid < 32) {
        float s = 0.f;
        for (int d = 0; d < 64; ++d) s += qs[d * 33 + tid] * bk[64 * h + d];
        ws[OFF_QBK + tid * H_ + h] = s * 0.125f;
    }
}

// ---------------------------------------------------------------- fused scores/softmax/u_part
// ROUND-4 VERBATIM (best measured: 164.7 us attn, 489 us total). 1024 threads, 64-VGPR
// budget; phase 1 = 16-float e-granule acc[16][2]; phase 2 = LDS double-buffered
// 8-row staging. Rounds 5-9 (t-LDS halving, x-LDS removal, lane-grouped wl reads,
// 512-thr ILP, manual prefetch) were all neutral-to-negative: the kernel sits at a
// latency plateau that none of those levers moved.
__global__ __launch_bounds__(1024) void k_attn_core(const float* __restrict__ x,
                                                    float* __restrict__ ws) {
    const int tile = blockIdx.x, b = blockIdx.y, tid = threadIdx.x;
    const int s0t = tile * STILE;
    const float* tmat = ws + OFF_T + (size_t)b * H_ * E_;
    const float* xb = x + (size_t)(b * L_ + 1 + s0t) * E_;

    __shared__ float smem[16384];   // t[16][1024] | ph2: 2 bufs of 8x1024 | combine: 8 planes
    __shared__ float wl[256 * 16];  // hi-half partial scores, then softmax weights [s][h]
    __shared__ float pmax[128], psum[128], msh[16];

    const int lane = tid & 63, w = tid >> 6;
    const int g = lane & 3, ssub = lane >> 2;
    const int wlo = w & 7;
    const int ehalf = (w >> 3) * 512;      // phase-1 e-half owned by this wave group
    const int sA = 32 * wlo + ssub, sB = sA + 16;

    // ---- stage full t (16x1024 = 64 KB), straight copy ----
    #pragma unroll
    for (int k = 0; k < 4; ++k) {
        int idx4 = k * 1024 + tid;
        *(float4*)&smem[4 * idx4] = *(const float4*)(tmat + 4 * idx4);
    }
    __syncthreads();

    // ================= phase 1: partial scores (no barriers inside) =================
    float acc[16][2];
    #pragma unroll
    for (int h = 0; h < 16; ++h) { acc[h][0] = 0.f; acc[h][1] = 0.f; }

    {
        // each quad lane g covers e = ehalf + 16*c + 4*g .. +3  (union over g = full half)
        const float* xA = xb + (size_t)sA * E_ + ehalf + 4 * g;
        const float* xB = xb + (size_t)sB * E_ + ehalf + 4 * g;
        const float* tb = &smem[ehalf + 4 * g];
        #pragma unroll 2
        for (int c = 0; c < 32; ++c) {
            float4 a0 = *(const float4*)(xA + 16 * c);
            float4 b0 = *(const float4*)(xB + 16 * c);
            #pragma unroll
            for (int h = 0; h < 16; ++h) {
                float4 t0 = *(const float4*)(tb + h * E_ + 16 * c);
                acc[h][0] += t0.x * a0.x + t0.y * a0.y + t0.z * a0.z + t0.w * a0.w;
                acc[h][1] += t0.x * b0.x + t0.y * b0.y + t0.z * b0.z + t0.w * b0.w;
            }
        }
    }
    // reduce over the 4 e-column lanes (g) — all 4 g-dups end with the full sum
    #pragma unroll
    for (int h = 0; h < 16; ++h) {
        #pragma unroll
        for (int s = 0; s < 2; ++s) {
            float v = acc[h][s];
            v += __shfl_xor(v, 1, 64);
            v += __shfl_xor(v, 2, 64);
            acc[h][s] = v;
        }
    }
    // hi e-half waves deposit partials into wl (g-branch picks the h-quad; static reg idx)
    if (w >= 8) {
        if (g == 0) {
            *(float4*)&wl[sA * 16 + 0]  = make_float4(acc[0][0], acc[1][0], acc[2][0], acc[3][0]);
            *(float4*)&wl[sB * 16 + 0]  = make_float4(acc[0][1], acc[1][1], acc[2][1], acc[3][1]);
        } else if (g == 1) {
            *(float4*)&wl[sA * 16 + 4]  = make_float4(acc[4][0], acc[5][0], acc[6][0], acc[7][0]);
            *(float4*)&wl[sB * 16 + 4]  = make_float4(acc[4][1], acc[5][1], acc[6][1], acc[7][1]);
        } else if (g == 2) {
            *(float4*)&wl[sA * 16 + 8]  = make_float4(acc[8][0], acc[9][0], acc[10][0], acc[11][0]);
            *(float4*)&wl[sB * 16 + 8]  = make_float4(acc[8][1], acc[9][1], acc[10][1], acc[11][1]);
        } else {
            *(float4*)&wl[sA * 16 + 12] = make_float4(acc[12][0], acc[13][0], acc[14][0], acc[15][0]);
            *(float4*)&wl[sB * 16 + 12] = make_float4(acc[12][1], acc[13][1], acc[14][1], acc[15][1]);
        }
    }
    __syncthreads();  // E1: hi partials visible; smem (t) free from here on

    // ================= softmax partials (lo waves hold full scores) =================
    if (w < 8) {
        const float* qbkp = ws + OFF_QBK + b * H_;
        #pragma unroll
        for (int h = 0; h < 16; ++h) {
            float qb = qbkp[h];
            acc[h][0] += wl[sA * 16 + h] + qb;
            acc[h][1] += wl[sB * 16 + h] + qb;
        }
        #pragma unroll
        for (int h = 0; h < 16; ++h) {
            float v = fmaxf(acc[h][0], acc[h][1]);
            v = fmaxf(v, __shfl_xor(v, 4, 64));
            v = fmaxf(v, __shfl_xor(v, 8, 64));
            v = fmaxf(v, __shfl_xor(v, 16, 64));
            v = fmaxf(v, __shfl_xor(v, 32, 64));
            if (lane == 0) pmax[w * 16 + h] = v;
        }
    }
    __syncthreads();  // B1
    if (tid < 16) {
        float M = pmax[tid];
        #pragma unroll
        for (int q = 1; q < 8; ++q) M = fmaxf(M, pmax[q * 16 + tid]);
        msh[tid] = M;
        ws[OFF_M + (size_t)(b * NT_ + tile) * H_ + tid] = M;
    }
    __syncthreads();  // B2
    if (w < 8) {
        float ex0[16], ex1[16];
        #pragma unroll
        for (int h = 0; h < 16; ++h) {
            float M = msh[h];
            ex0[h] = __expf(acc[h][0] - M);
            ex1[h] = __expf(acc[h][1] - M);
        }
        if (g == 0) {
            *(float4*)&wl[sA * 16 + 0]  = make_float4(ex0[0], ex0[1], ex0[2], ex0[3]);
            *(float4*)&wl[sB * 16 + 0]  = make_float4(ex1[0], ex1[1], ex1[2], ex1[3]);
        } else if (g == 1) {
            *(float4*)&wl[sA * 16 + 4]  = make_float4(ex0[4], ex0[5], ex0[6], ex0[7]);
            *(float4*)&wl[sB * 16 + 4]  = make_float4(ex1[4], ex1[5], ex1[6], ex1[7]);
        } else if (g == 2) {
            *(float4*)&wl[sA * 16 + 8]  = make_float4(ex0[8], ex0[9], ex0[10], ex0[11]);
            *(float4*)&wl[sB * 16 + 8]  = make_float4(ex1[8], ex1[9], ex1[10], ex1[11]);
        } else {
            *(float4*)&wl[sA * 16 + 12] = make_float4(ex0[12], ex0[13], ex0[14], ex0[15]);
            *(float4*)&wl[sB * 16 + 12] = make_float4(ex1[12], ex1[13], ex1[14], ex1[15]);
        }
        #pragma unroll
        for (int h = 0; h < 16; ++h) {
            float v = ex0[h] + ex1[h];
            v += __shfl_xor(v, 4, 64);
            v += __shfl_xor(v, 8, 64);
            v += __shfl_xor(v, 16, 64);
            v += __shfl_xor(v, 32, 64);
            if (lane == 0) psum[w * 16 + h] = v;
        }
    }
    __syncthreads();  // B3: weights complete; smem fully free for phase-2 buffers
    if (tid < 16) {
        float Ls = 0.f;
        #pragma unroll
        for (int q = 0; q < 8; ++q) Ls += psum[q * 16 + tid];
        ws[OFF_L + (size_t)(b * NT_ + tile) * H_ + tid] = Ls;
    }

    // ================= phase 2: u_part[h][e] = sum_s w[s][h]*x[s][e] =================
    const int hp = w & 7, shalf = w >> 3;
    float4 accA[4], accB[4];
    #pragma unroll
    for (int j = 0; j < 4; ++j) {
        accA[j] = make_float4(0.f, 0.f, 0.f, 0.f);
        accB[j] = make_float4(0.f, 0.f, 0.f, 0.f);
    }
    const int r0 = tid >> 8, c4 = tid & 255;  // staging: 2 float4/thread per 8-row chunk
    float4 st0 = *(const float4*)(xb + (size_t)(r0)     * E_ + 4 * c4);
    float4 st1 = *(const float4*)(xb + (size_t)(r0 + 4) * E_ + 4 * c4);
    *(float4*)&smem[(r0)     * 1024 + 4 * c4] = st0;
    *(float4*)&smem[(r0 + 4) * 1024 + 4 * c4] = st1;
    for (int c = 0; c < 32; ++c) {
        __syncthreads();
        if (c + 1 < 32) {
            st0 = *(const float4*)(xb + (size_t)(8 * (c + 1) + r0)     * E_ + 4 * c4);
            st1 = *(const float4*)(xb + (size_t)(8 * (c + 1) + r0 + 4) * E_ + 4 * c4);
        }
        const float* A = &smem[(c & 1) * 8192];
        #pragma unroll
        for (int rr = 0; rr < 4; ++rr) {
            const int r = 4 * shalf + rr;
            float2 wv = *(const float2*)&wl[(8 * c + r) * 16 + 2 * hp];
            #pragma unroll
            for (int ej = 0; ej < 4; ++ej) {
                float4 xv = *(const float4*)&A[r * 1024 + 4 * lane + 256 * ej];
                accA[ej].x += wv.x * xv.x; accA[ej].y += wv.x * xv.y;
                accA[ej].z += wv.x * xv.z; accA[ej].w += wv.x * xv.w;
                accB[ej].x += wv.y * xv.x; accB[ej].y += wv.y * xv.y;
                accB[ej].z += wv.y * xv.z; accB[ej].w += wv.y * xv.w;
            }
        }
        if (c + 1 < 32) {
            float* D = &smem[((c + 1) & 1) * 8192];
            *(float4*)&D[(r0)     * 1024 + 4 * c4] = st0;
            *(float4*)&D[(r0 + 4) * 1024 + 4 * c4] = st1;
        }
    }
    __syncthreads();  // all chunk reads done before smem reuse for combine
    if (shalf == 1) {
        #pragma unroll
        for (int ej = 0; ej < 4; ++ej) {
            *(float4*)&smem[hp * 2048 +        4 * lane + 256 * ej] = accA[ej];
            *(float4*)&smem[hp * 2048 + 1024 + 4 * lane + 256 * ej] = accB[ej];
        }
    }
    __syncthreads();
    if (shalf == 0) {
        float* up = ws + OFF_UP + ((size_t)(b * NT_ + tile) * H_ + 2 * hp) * E_;
        #pragma unroll
        for (int ej = 0; ej < 4; ++ej) {
            float4 pA = *(const float4*)&smem[hp * 2048 +        4 * lane + 256 * ej];
            float4 pB = *(const float4*)&smem[hp * 2048 + 1024 + 4 * lane + 256 * ej];
            float4 oA = make_float4(accA[ej].x + pA.x, accA[ej].y + pA.y,
                                    accA[ej].z + pA.z, accA[ej].w + pA.w);
            float4 oB = make_float4(accB[ej].x + pB.x, accB[ej].y + pB.y,
                                    accB[ej].z + pB.z, accB[ej].w + pB.w);
            *(float4*)(up +       4 * lane + 256 * ej) = oA;
            *(float4*)(up + E_ +  4 * lane + 256 * ej) = oB;
        }
    }
}

// ---------------------------------------------------------------- fused combine + V-proj:
// attn[b][j] = sum_k u_norm[b][h][k] * Wv[j][k] + bv[j], h = j>>6, where
// u_norm[b][h][k] = inv * sum_tg f[tg] * UP[((b*NT+tg)*H+h)*E + k].
// grid (B, H), 256 thr (4 waves). Lane owns u chunk [16*lane, 16*lane+16) in registers
// (no LDS, no barriers); wave w computes rows j = 64h + 16w + dd via coalesced 4-KB
// Wv row reads + 6-step shfl_xor reduce. Replaces k_combine + k_gemm32(Wv): one fewer
// dispatch, no u round-trip through global.
__global__ __launch_bounds__(256) void k_vproj(const float* __restrict__ Wv,
                                               const float* __restrict__ bv,
                                               float* __restrict__ ws) {
    const int b = blockIdx.x, h = blockIdx.y, tid = threadIdx.x;
    const int lane = tid & 63, w = tid >> 6;

    // combine factors (redundant per-thread, 16 scalar loads)
    float m[NT_], f[NT_];
    float M = -1e30f;
    #pragma unroll
    for (int tg = 0; tg < NT_; ++tg) {
        m[tg] = ws[OFF_M + (b * NT_ + tg) * H_ + h];
        M = fmaxf(M, m[tg]);
    }
    float Ls = 0.f;
    #pragma unroll
    for (int tg = 0; tg < NT_; ++tg) {
        f[tg] = __expf(m[tg] - M);
        Ls += f[tg] * ws[OFF_L + (b * NT_ + tg) * H_ + h];
    }
    const float inv = 1.f / Ls;

    // u chunk in registers: u[16*lane .. 16*lane+16)
    float4 u0 = make_float4(0.f, 0.f, 0.f, 0.f), u1 = u0, u2 = u0, u3 = u0;
    const float* upb = ws + OFF_UP + ((size_t)(b * NT_) * H_ + h) * E_ + 16 * lane;
    #pragma unroll
    for (int tg = 0; tg < NT_; ++tg) {
        const float* p = upb + (size_t)tg * H_ * E_;
        float4 a0 = *(const float4*)(p);
        float4 a1 = *(const float4*)(p + 4);
        float4 a2 = *(const float4*)(p + 8);
        float4 a3 = *(const float4*)(p + 12);
        const float ft = f[tg];
        u0.x += ft * a0.x; u0.y += ft * a0.y; u0.z += ft * a0.z; u0.w += ft * a0.w;
        u1.x += ft * a1.x; u1.y += ft * a1.y; u1.z += ft * a1.z; u1.w += ft * a1.w;
        u2.x += ft * a2.x; u2.y += ft * a2.y; u2.z += ft * a2.z; u2.w += ft * a2.w;
        u3.x += ft * a3.x; u3.y += ft * a3.y; u3.z += ft * a3.z; u3.w += ft * a3.w;
    }
    u0.x *= inv; u0.y *= inv; u0.z *= inv; u0.w *= inv;
    u1.x *= inv; u1.y *= inv; u1.z *= inv; u1.w *= inv;
    u2.x *= inv; u2.y *= inv; u2.z *= inv; u2.w *= inv;
    u3.x *= inv; u3.y *= inv; u3.z *= inv; u3.w *= inv;

    // 16 Wv rows per wave; coalesced row reads; cross-lane reduce
    #pragma unroll 2
    for (int dd = 0; dd < 16; ++dd) {
        const int j = 64 * h + 16 * w + dd;
        const float* wr = Wv + (size_t)j * E_ + 16 * lane;
        float4 v0 = *(const float4*)(wr);
        float4 v1 = *(const float4*)(wr + 4);
        float4 v2 = *(const float4*)(wr + 8);
        float4 v3 = *(const float4*)(wr + 12);
        float s = u0.x * v0.x + u0.y * v0.y + u0.z * v0.z + u0.w * v0.w
                + u1.x * v1.x + u1.y * v1.y + u1.z * v1.z + u1.w * v1.w
                + u2.x * v2.x + u2.y * v2.y + u2.z * v2.z + u2.w * v2.w
                + u3.x * v3.x + u3.y * v3.y + u3.z * v3.z + u3.w * v3.w;
        s += __shfl_xor(s, 1, 64);
        s += __shfl_xor(s, 2, 64);
        s += __shfl_xor(s, 4, 64);
        s += __shfl_xor(s, 8, 64);
        s += __shfl_xor(s, 16, 64);
        s += __shfl_xor(s, 32, 64);
        if (lane == 0)
            ws[OFF_ATTN + (size_t)b * E_ + j] = s + bv[j];
    }
}

// ---------------------------------------------------------------- LayerNorm -> out
__global__ __launch_bounds__(256) void k_ln(const float* __restrict__ ws,
                                            const float* __restrict__ g,
                                            const float* __restrict__ be,
                                            float* __restrict__ out) {
    const int b = blockIdx.x, tid = threadIdx.x;
    const float* y = ws + OFF_Y + (size_t)b * E_;
    float4 v = *(const float4*)(y + 4 * tid);
    float s = v.x + v.y + v.z + v.w;
    float s2 = v.x * v.x + v.y * v.y + v.z * v.z + v.w * v.w;
    for (int o = 32; o; o >>= 1) {
        s += __shfl_down(s, o, 64);
        s2 += __shfl_down(s2, o, 64);
    }
    __shared__ float rs[4], rs2[4];
    int ww = tid >> 6;
    if ((tid & 63) == 0) { rs[ww] = s; rs2[ww] = s2; }
    __syncthreads();
    float S = rs[0] + rs[1] + rs[2] + rs[3];
    float S2 = rs2[0] + rs2[1] + rs2[2] + rs2[3];
    float mean = S * (1.f / 1024.f);
    float var = S2 * (1.f / 1024.f) - mean * mean;
    float r = rsqrtf(var + 1e-5f);
    float4 gv = *(const float4*)(g + 4 * tid);
    float4 bb2 = *(const float4*)(be + 4 * tid);
    float4 o;
    o.x = (v.x - mean) * r * gv.x + bb2.x;
    o.y = (v.y - mean) * r * gv.y + bb2.y;
    o.z = (v.z - mean) * r * gv.z + bb2.z;
    o.w = (v.w - mean) * r * gv.w + bb2.w;
    *(float4*)(out + (size_t)b * E_ + 4 * tid) = o;
}

extern "C" void kernel_launch(void* const* d_in, const int* in_sizes, int n_in,
                              void* d_out, int out_size, void* d_ws, size_t ws_size,
                              hipStream_t stream) {
    const float* x  = (const float*)d_in[0];
    const float* Wq = (const float*)d_in[1];
    const float* bq = (const float*)d_in[2];
    const float* Wk = (const float*)d_in[3];
    const float* bk = (const float*)d_in[4];
    const float* Wv = (const float*)d_in[5];
    const float* bv = (const float*)d_in[6];
    const float* Wo = (const float*)d_in[7];
    const float* bo = (const float*)d_in[8];
    const float* g  = (const float*)d_in[9];
    const float* be = (const float*)d_in[10];
    float* ws = (float*)d_ws;
    float* out = (float*)d_out;

    // q = cls @ Wq^T + bq
    k_gemm32<<<512, 256, 0, stream>>>(x, (long long)L_ * E_, 0, Wq, bq, nullptr, 0, ws + OFF_Q);
    // t = 0.125 * q_h @ Wk_h ; qbk
    k_tproj<<<dim3(16, 16), 256, 0, stream>>>(Wk, bk, ws);
    // fused attention core (round-4 version)
    k_attn_core<<<dim3(NT_, B_), 1024, 0, stream>>>(x, ws);
    // fused combine + V-projection
    k_vproj<<<dim3(B_, H_), 256, 0, stream>>>(Wv, bv, ws);
    // y = attn @ Wo^T + bo + cls
    k_gemm32<<<512, 256, 0, stream>>>(ws + OFF_ATTN, (long long)E_, 0, Wo, bo, x, (long long)L_ * E_, ws + OFF_Y);
    // LayerNorm
    k_ln<<<B_, 256, 0, stream>>>(ws, g, be, out);
}